// Round 16
// baseline (112.963 us; speedup 1.0000x reference)
//
#include <hip/hip_runtime.h>
#include <math.h>

#define CIN 64
#define NP 128

typedef float f32x4 __attribute__((ext_vector_type(4)));
typedef short s16x8 __attribute__((ext_vector_type(8)));
typedef short s16x4 __attribute__((ext_vector_type(4)));

union FragU { s16x8 v; unsigned u[4]; };
union Frag4 { s16x4 v; unsigned u[2]; };

static __device__ __forceinline__ unsigned short f2b(float f) {
    unsigned u = __builtin_bit_cast(unsigned, f);
    unsigned r = (u + 0x7FFFu + ((u >> 16) & 1u)) >> 16;   // RNE (proven R1/R2/R5/R8)
    return (unsigned short)r;
}
// pack two f32 -> bf16x2 word, software RNE — NOT v_cvt_pk (R6: raw instr != RNE)
static __device__ __forceinline__ unsigned pack2(float lo, float hi) {
    return (unsigned)f2b(lo) | ((unsigned)f2b(hi) << 16);
}

// 16x16x16 bf16 MFMA (gfx950 instruction per ISA §10; carried-forward builtin)
static __device__ __forceinline__ f32x4 mfma16(s16x4 a, s16x4 b, f32x4 c) {
#if __has_builtin(__builtin_amdgcn_mfma_f32_16x16x16bf16_1k)
    return __builtin_amdgcn_mfma_f32_16x16x16bf16_1k(a, b, c, 0, 0, 0);
#else
    asm volatile("v_mfma_f32_16x16x16_bf16 %0, %1, %2, %0\n\ts_nop 7\n\ts_nop 7"
                 : "+v"(c) : "v"(a), "v"(b));
    return c;
#endif
}

// K0: pack W_k, W_v (rows 128..383 of Wqkv) into bf16 MFMA fragment tiles.
__global__ __launch_bounds__(256) void prep_w(const float* __restrict__ Wqkv,
                                              unsigned short* __restrict__ Wb) {
    int e0 = (blockIdx.x * 256 + threadIdx.x) * 8;   // < 16384
    int lane = (e0 >> 3) & 63;
    int kc = (e0 >> 9) & 1;
    int t = e0 >> 10;
    int row = 128 + t * 16 + (lane & 15);
    int c0 = kc * 32 + (lane >> 4) * 8;
    for (int j = 0; j < 8; ++j)
        Wb[e0 + j] = f2b(Wqkv[row * 64 + c0 + j]);
}

// K1: fused kv-projection + exp + context, all in registers (proven R14/R15).
// TWO heads per block (R15 post-mortem: 4 head-blocks -> 4 x-streams -> FETCH
// 2x x = 110MB was the whole kernel time; R10 proved 2 streams fully L3-absorb).
// W fragments re-loaded from L1 per chunk instead of hoisted (saves 64 VGPR ->
// no spill at the (256,3) 168-reg cap); x load+pack amortized over both heads.
__global__ __launch_bounds__(256, 3) void lin_attn_ctx(
    const float* __restrict__ x, const unsigned short* __restrict__ Wb,
    float* __restrict__ P, int n, int nch)
{
    __shared__ float RED[4224];          // epilogue-only: 4x1024 ctx + 4x32 sums

    const int tid = threadIdx.x;
    const int l = tid & 63;
    const int w = tid >> 6;
    const int h0 = blockIdx.x * 2;       // head pair (fastest)
    const int b = blockIdx.y;            // batch
    const int slot = blockIdx.z;         // chunk slot
    const int nslot = gridDim.z;
    const int l15 = l & 15, lg = l >> 4;
    const uint4* Wb4 = (const uint4*)Wb;

    f32x4 zero4 = {0.f, 0.f, 0.f, 0.f};
    f32x4 ctx[2][2][2];                  // [hh][rt][vt]
    float sacc[2][2] = {{0.f, 0.f}, {0.f, 0.f}};
#pragma unroll
    for (int hh = 0; hh < 2; ++hh)
#pragma unroll
        for (int a = 0; a < 2; ++a)
#pragma unroll
            for (int c2 = 0; c2 < 2; ++c2) ctx[hh][a][c2] = zero4;

    const float* xw = x + (size_t)b * CIN * n;

    for (int ch = slot; ch < nch; ch += nslot) {
        // ---- direct global -> X-fragment loads, pack immediately (shared by both heads) ----
        const float* xp = xw + ch * NP + w * 32 + l15;
        s16x8 bx[2][2];
#pragma unroll
        for (int pt = 0; pt < 2; ++pt)
#pragma unroll
            for (int kc = 0; kc < 2; ++kc) {
                float xv[8];
#pragma unroll
                for (int j = 0; j < 8; ++j)
                    xv[j] = xp[(size_t)(kc * 32 + lg * 8 + j) * n + pt * 16];
                FragU fu;
#pragma unroll
                for (int i = 0; i < 4; ++i)
                    fu.u[i] = pack2(xv[2 * i], xv[2 * i + 1]);
                bx[pt][kc] = fu.v;
            }

#pragma unroll
        for (int hh = 0; hh < 2; ++hh) {
            const int h = h0 + hh;
            // W fragments from L1 (32KB Wb is hot; independent loads pipeline)
            s16x8 ak[2][2], av[2][2];
#pragma unroll
            for (int rt = 0; rt < 2; ++rt)
#pragma unroll
                for (int kc = 0; kc < 2; ++kc) {
                    ak[rt][kc] = *(const s16x8*)&Wb4[((2 * h + rt) * 2 + kc) * 64 + l];
                    av[rt][kc] = *(const s16x8*)&Wb4[((8 + 2 * h + rt) * 2 + kc) * 64 + l];
                }

            // ---- swapped projection -> exp -> pack (all registers) ----
            Frag4 ekf[2][2], vf[2][2];       // [pt][rt]
#pragma unroll
            for (int pt = 0; pt < 2; ++pt) {
#pragma unroll
                for (int rt = 0; rt < 2; ++rt) {
                    f32x4 z = zero4;
                    z = __builtin_amdgcn_mfma_f32_16x16x32_bf16(bx[pt][0], ak[rt][0], z, 0, 0, 0);
                    z = __builtin_amdgcn_mfma_f32_16x16x32_bf16(bx[pt][1], ak[rt][1], z, 0, 0, 0);
                    f32x4 z2 = zero4;
                    z2 = __builtin_amdgcn_mfma_f32_16x16x32_bf16(bx[pt][0], av[rt][0], z2, 0, 0, 0);
                    z2 = __builtin_amdgcn_mfma_f32_16x16x32_bf16(bx[pt][1], av[rt][1], z2, 0, 0, 0);
                    float e0 = __expf(z[0]), e1 = __expf(z[1]);
                    float e2 = __expf(z[2]), e3 = __expf(z[3]);
                    sacc[hh][rt] += (e0 + e1) + (e2 + e3);
                    Frag4 fe; fe.u[0] = pack2(e0, e1); fe.u[1] = pack2(e2, e3);
                    ekf[pt][rt] = fe;
                    Frag4 fv; fv.u[0] = pack2(z2[0], z2[1]); fv.u[1] = pack2(z2[2], z2[3]);
                    vf[pt][rt] = fv;
                }
            }
            // ---- context: ctx[hh][rt][vt] += EK x V^T, K=pos ----
#pragma unroll
            for (int rt = 0; rt < 2; ++rt)
#pragma unroll
                for (int vt = 0; vt < 2; ++vt) {
                    ctx[hh][rt][vt] = mfma16(ekf[0][rt].v, vf[0][vt].v, ctx[hh][rt][vt]);
                    ctx[hh][rt][vt] = mfma16(ekf[1][rt].v, vf[1][vt].v, ctx[hh][rt][vt]);
                }
        }
    }

    // ---- cross-wave reduce, write both heads' partials ----
    float* Xf = RED;
    float* Sf = RED + 4096;
    float* Pb = P + (size_t)(b * nslot + slot) * 4224;
#pragma unroll
    for (int hh = 0; hh < 2; ++hh) {
        const int h = h0 + hh;
        __syncthreads();   // hh=0: trivial; hh=1: all waves done reading Xf
#pragma unroll
        for (int rt = 0; rt < 2; ++rt)
#pragma unroll
            for (int vt = 0; vt < 2; ++vt)
#pragma unroll
                for (int r = 0; r < 4; ++r) {
                    int d = rt * 16 + lg * 4 + r, e = vt * 16 + l15;
                    Xf[w * 1024 + d * 32 + e] = ctx[hh][rt][vt][r];
                }
#pragma unroll
        for (int rt = 0; rt < 2; ++rt) {
            float s = sacc[hh][rt];
            s += __shfl_xor(s, 16);
            s += __shfl_xor(s, 32);
            if (l < 16) Sf[w * 32 + rt * 16 + l15] = s;
        }
        __syncthreads();
        for (int i = tid; i < 1024; i += 256)
            Pb[h * 1056 + i] = Xf[i] + Xf[1024 + i] + Xf[2048 + i] + Xf[3072 + i];
        if (tid < 32)
            Pb[h * 1056 + 1024 + tid] = Sf[tid] + Sf[32 + tid] + Sf[64 + tid] + Sf[96 + tid];
    }
}

// K2a: slot-sliced partial reduce: P[b][slot][4224] -> P2[b][16][4224]
__global__ __launch_bounds__(256) void reduce_p1(
    const float* __restrict__ P, float* __restrict__ P2, int nblk)
{
    const int idx = blockIdx.x * 256 + threadIdx.x;
    if (idx >= 4224) return;
    const int b = blockIdx.z, sz = blockIdx.y;
    float acc = 0.f;
    for (int slot = sz; slot < nblk; slot += 16)
        acc += P[((size_t)(b * nblk + slot)) * 4224 + idx];
    P2[((size_t)(b * 16 + sz)) * 4224 + idx] = acc;
}

// K2b: final reduce -> R[b][4224]
__global__ __launch_bounds__(256) void reduce_p2(
    const float* __restrict__ P2, float* __restrict__ R)
{
    const int idx = blockIdx.x * 256 + threadIdx.x;
    if (idx >= 4224) return;
    const int b = blockIdx.y;
    float acc = 0.f;
#pragma unroll
    for (int s = 0; s < 16; ++s)
        acc += P2[((size_t)(b * 16 + s)) * 4224 + idx];
    R[b * 4224 + idx] = acc;
}

// K3: build Mt[c][o], parallelized over (o-slice=8, batch) = 16 blocks (R15).
__global__ __launch_bounds__(256) void build_M(
    const float* __restrict__ R, const float* __restrict__ Wout,
    const float* __restrict__ Wqkv, float* __restrict__ Mt)
{
    __shared__ float ctx[4096];          // [h][e][d] (transposed)
    __shared__ float Ash[8 * 128];       // A[oo][h*32+d]
    const int b = blockIdx.y;
    const int o0 = blockIdx.x * 8;
    const int tid = threadIdx.x;
    const float* Rb = R + b * 4224;
    for (int i = tid; i < 4096; i += 256) {
        const int hh = i >> 10, rr = i & 1023, e = rr >> 5, d = rr & 31;
        ctx[i] = Rb[hh * 1056 + d * 32 + e] / Rb[hh * 1056 + 1024 + d];
    }
    __syncthreads();
    for (int i = tid; i < 1024; i += 256) {
        const int oo = i >> 7, m = i & 127, hh = m >> 5, d = m & 31;
        float acc = 0.f;
#pragma unroll
        for (int e = 0; e < 32; ++e)
            acc += Wout[(o0 + oo) * 128 + hh * 32 + e] * ctx[hh * 1024 + e * 32 + d];
        Ash[i] = acc;
    }
    __syncthreads();
    const float scale = 0.17677669529663687f;
    for (int i = tid; i < 512; i += 256) {
        const int oo = i >> 6, c = i & 63;
        float acc = 0.f;
#pragma unroll
        for (int m = 0; m < 128; ++m)
            acc += Ash[oo * 128 + m] * Wqkv[m * 64 + c];
        Mt[b * 4096 + c * 64 + (o0 + oo)] = acc * scale;   // transposed store
    }
}

// K4: y[b,o,p] = sum_c Mt[c][o] x[b,c,p] + b_out[o]
__global__ __launch_bounds__(256, 4) void final_proj(
    const float* __restrict__ x, const float* __restrict__ Mt,
    const float* __restrict__ bout, float* __restrict__ y, int n)
{
    const int b = blockIdx.y;
    const int p = blockIdx.x * 256 + threadIdx.x;
    const float* xb = x + (size_t)b * CIN * n + p;
    const float* M = Mt + b * 4096;
    float acc[64];
#pragma unroll
    for (int o = 0; o < 64; ++o) acc[o] = bout[o];
    for (int c = 0; c < 64; ++c) {
        const float xv = xb[(size_t)c * n];
        const float* Mr = M + c * 64;
#pragma unroll
        for (int o = 0; o < 64; ++o) acc[o] += Mr[o] * xv;
    }
    float* yb = y + (size_t)b * CIN * n + p;
#pragma unroll
    for (int o = 0; o < 64; ++o) yb[(size_t)o * n] = acc[o];
}

extern "C" void kernel_launch(void* const* d_in, const int* in_sizes, int n_in,
                              void* d_out, int out_size, void* d_ws, size_t ws_size,
                              hipStream_t stream) {
    const float* x    = (const float*)d_in[0];
    const float* Wqkv = (const float*)d_in[1];
    const float* Wout = (const float*)d_in[2];
    const float* bout = (const float*)d_in[3];
    float* y = (float*)d_out;

    const int n = in_sizes[0] / 128;   // 110592
    const int nch = n / NP;            // 864

    // ws-adaptive partial-slot count
    int BLKX = 432;
    for (;;) {
        size_t need = 32768 + (size_t)2 * BLKX * 4224 * 4   // P
                    + (size_t)2 * 16 * 4224 * 4             // P2
                    + 2 * 4224 * 4 + 2 * 4096 * 4;          // R, Mt
        if (need <= ws_size || BLKX <= 64) break;
        BLKX = (BLKX == 432) ? 256 : (BLKX >> 1);
    }
    unsigned short* Wb = (unsigned short*)d_ws;                  // 32 KiB
    float* P  = (float*)((char*)d_ws + 32768);
    float* P2 = P + (size_t)2 * BLKX * 4224;
    float* R  = P2 + (size_t)2 * 16 * 4224;
    float* Mt = R + 2 * 4224;

    prep_w<<<8, 256, 0, stream>>>(Wqkv, Wb);
    lin_attn_ctx<<<dim3(2, 2, BLKX), 256, 0, stream>>>(x, Wb, P, n, nch);
    reduce_p1<<<dim3(17, 16, 2), 256, 0, stream>>>(P, P2, BLKX);
    reduce_p2<<<dim3(17, 2), 256, 0, stream>>>(P2, R);
    build_M<<<dim3(8, 2), 256, 0, stream>>>(R, Wout, Wqkv, Mt);
    final_proj<<<dim3(n / 256, 2), 256, 0, stream>>>(x, Mt, bout, y, n);
}

// Round 17
// 89.078 us; speedup vs baseline: 1.2681x; 1.2681x over previous
//
#include <hip/hip_runtime.h>
#include <math.h>

#define CIN 64
#define NP 128

typedef float f32x4 __attribute__((ext_vector_type(4)));
typedef short s16x8 __attribute__((ext_vector_type(8)));
typedef short s16x4 __attribute__((ext_vector_type(4)));

union FragU { s16x8 v; unsigned u[4]; };
union Frag4 { s16x4 v; unsigned u[2]; };

static __device__ __forceinline__ unsigned short f2b(float f) {
    unsigned u = __builtin_bit_cast(unsigned, f);
    unsigned r = (u + 0x7FFFu + ((u >> 16) & 1u)) >> 16;   // RNE (proven R1/R2/R5/R8)
    return (unsigned short)r;
}
// pack two f32 -> bf16x2 word, software RNE — NOT v_cvt_pk (R6: raw instr != RNE)
static __device__ __forceinline__ unsigned pack2(float lo, float hi) {
    return (unsigned)f2b(lo) | ((unsigned)f2b(hi) << 16);
}

// 16x16x16 bf16 MFMA (gfx950 instruction per ISA §10; carried-forward builtin)
static __device__ __forceinline__ f32x4 mfma16(s16x4 a, s16x4 b, f32x4 c) {
#if __has_builtin(__builtin_amdgcn_mfma_f32_16x16x16bf16_1k)
    return __builtin_amdgcn_mfma_f32_16x16x16bf16_1k(a, b, c, 0, 0, 0);
#else
    asm volatile("v_mfma_f32_16x16x16_bf16 %0, %1, %2, %0\n\ts_nop 7\n\ts_nop 7"
                 : "+v"(c) : "v"(a), "v"(b));
    return c;
#endif
}

// K0: pack W_k, W_v (rows 128..383 of Wqkv) into bf16 MFMA fragment tiles.
__global__ __launch_bounds__(256) void prep_w(const float* __restrict__ Wqkv,
                                              unsigned short* __restrict__ Wb) {
    int e0 = (blockIdx.x * 256 + threadIdx.x) * 8;   // < 16384
    int lane = (e0 >> 3) & 63;
    int kc = (e0 >> 9) & 1;
    int t = e0 >> 10;
    int row = 128 + t * 16 + (lane & 15);
    int c0 = kc * 32 + (lane >> 4) * 8;
    for (int j = 0; j < 8; ++j)
        Wb[e0 + j] = f2b(Wqkv[row * 64 + c0 + j]);
}

// K1: fused kv-projection + exp + context, all in registers (proven R14/R15).
// TWO heads per block (halves the x FETCH — R10/R15/R16 stream evidence) at
// __launch_bounds__(256,2): the 256-reg budget fits the ~140-reg live state
// with NO spill (R16 post-mortem: (256,3)'s 168 cap spilled -> VGPR 84 tier,
// +45MB scratch writes; R9 precedent: (256,2) -> no scratch).
__global__ __launch_bounds__(256, 2) void lin_attn_ctx(
    const float* __restrict__ x, const unsigned short* __restrict__ Wb,
    float* __restrict__ P, int n, int nch)
{
    __shared__ float RED[4224];          // epilogue-only: 4x1024 ctx + 4x32 sums

    const int tid = threadIdx.x;
    const int l = tid & 63;
    const int w = tid >> 6;
    const int h0 = blockIdx.x * 2;       // head pair (fastest)
    const int b = blockIdx.y;            // batch
    const int slot = blockIdx.z;         // chunk slot
    const int nslot = gridDim.z;
    const int l15 = l & 15, lg = l >> 4;
    const uint4* Wb4 = (const uint4*)Wb;

    f32x4 zero4 = {0.f, 0.f, 0.f, 0.f};
    f32x4 ctx[2][2][2];                  // [hh][rt][vt]
    float sacc[2][2] = {{0.f, 0.f}, {0.f, 0.f}};
#pragma unroll
    for (int hh = 0; hh < 2; ++hh)
#pragma unroll
        for (int a = 0; a < 2; ++a)
#pragma unroll
            for (int c2 = 0; c2 < 2; ++c2) ctx[hh][a][c2] = zero4;

    const float* xw = x + (size_t)b * CIN * n;

    for (int ch = slot; ch < nch; ch += nslot) {
        // ---- direct global -> X-fragment loads, pack immediately (shared by both heads) ----
        const float* xp = xw + ch * NP + w * 32 + l15;
        s16x8 bx[2][2];
#pragma unroll
        for (int pt = 0; pt < 2; ++pt)
#pragma unroll
            for (int kc = 0; kc < 2; ++kc) {
                float xv[8];
#pragma unroll
                for (int j = 0; j < 8; ++j)
                    xv[j] = xp[(size_t)(kc * 32 + lg * 8 + j) * n + pt * 16];
                FragU fu;
#pragma unroll
                for (int i = 0; i < 4; ++i)
                    fu.u[i] = pack2(xv[2 * i], xv[2 * i + 1]);
                bx[pt][kc] = fu.v;
            }

#pragma unroll
        for (int hh = 0; hh < 2; ++hh) {
            const int h = h0 + hh;
            // W fragments from L1 (32KB Wb is hot; independent loads pipeline)
            s16x8 ak[2][2], av[2][2];
#pragma unroll
            for (int rt = 0; rt < 2; ++rt)
#pragma unroll
                for (int kc = 0; kc < 2; ++kc) {
                    ak[rt][kc] = *(const s16x8*)&Wb4[((2 * h + rt) * 2 + kc) * 64 + l];
                    av[rt][kc] = *(const s16x8*)&Wb4[((8 + 2 * h + rt) * 2 + kc) * 64 + l];
                }

            // ---- swapped projection -> exp -> pack (all registers) ----
            Frag4 ekf[2][2], vf[2][2];       // [pt][rt]
#pragma unroll
            for (int pt = 0; pt < 2; ++pt) {
#pragma unroll
                for (int rt = 0; rt < 2; ++rt) {
                    f32x4 z = zero4;
                    z = __builtin_amdgcn_mfma_f32_16x16x32_bf16(bx[pt][0], ak[rt][0], z, 0, 0, 0);
                    z = __builtin_amdgcn_mfma_f32_16x16x32_bf16(bx[pt][1], ak[rt][1], z, 0, 0, 0);
                    f32x4 z2 = zero4;
                    z2 = __builtin_amdgcn_mfma_f32_16x16x32_bf16(bx[pt][0], av[rt][0], z2, 0, 0, 0);
                    z2 = __builtin_amdgcn_mfma_f32_16x16x32_bf16(bx[pt][1], av[rt][1], z2, 0, 0, 0);
                    float e0 = __expf(z[0]), e1 = __expf(z[1]);
                    float e2 = __expf(z[2]), e3 = __expf(z[3]);
                    sacc[hh][rt] += (e0 + e1) + (e2 + e3);
                    Frag4 fe; fe.u[0] = pack2(e0, e1); fe.u[1] = pack2(e2, e3);
                    ekf[pt][rt] = fe;
                    Frag4 fv; fv.u[0] = pack2(z2[0], z2[1]); fv.u[1] = pack2(z2[2], z2[3]);
                    vf[pt][rt] = fv;
                }
            }
            // ---- context: ctx[hh][rt][vt] += EK x V^T, K=pos ----
#pragma unroll
            for (int rt = 0; rt < 2; ++rt)
#pragma unroll
                for (int vt = 0; vt < 2; ++vt) {
                    ctx[hh][rt][vt] = mfma16(ekf[0][rt].v, vf[0][vt].v, ctx[hh][rt][vt]);
                    ctx[hh][rt][vt] = mfma16(ekf[1][rt].v, vf[1][vt].v, ctx[hh][rt][vt]);
                }
        }
    }

    // ---- cross-wave reduce, write both heads' partials ----
    float* Xf = RED;
    float* Sf = RED + 4096;
    float* Pb = P + (size_t)(b * nslot + slot) * 4224;
#pragma unroll
    for (int hh = 0; hh < 2; ++hh) {
        const int h = h0 + hh;
        __syncthreads();   // hh=0: trivial; hh=1: all waves done reading Xf
#pragma unroll
        for (int rt = 0; rt < 2; ++rt)
#pragma unroll
            for (int vt = 0; vt < 2; ++vt)
#pragma unroll
                for (int r = 0; r < 4; ++r) {
                    int d = rt * 16 + lg * 4 + r, e = vt * 16 + l15;
                    Xf[w * 1024 + d * 32 + e] = ctx[hh][rt][vt][r];
                }
#pragma unroll
        for (int rt = 0; rt < 2; ++rt) {
            float s = sacc[hh][rt];
            s += __shfl_xor(s, 16);
            s += __shfl_xor(s, 32);
            if (l < 16) Sf[w * 32 + rt * 16 + l15] = s;
        }
        __syncthreads();
        for (int i = tid; i < 1024; i += 256)
            Pb[h * 1056 + i] = Xf[i] + Xf[1024 + i] + Xf[2048 + i] + Xf[3072 + i];
        if (tid < 32)
            Pb[h * 1056 + 1024 + tid] = Sf[tid] + Sf[32 + tid] + Sf[64 + tid] + Sf[96 + tid];
    }
}

// K2a: slot-sliced partial reduce: P[b][slot][4224] -> P2[b][16][4224]
__global__ __launch_bounds__(256) void reduce_p1(
    const float* __restrict__ P, float* __restrict__ P2, int nblk)
{
    const int idx = blockIdx.x * 256 + threadIdx.x;
    if (idx >= 4224) return;
    const int b = blockIdx.z, sz = blockIdx.y;
    float acc = 0.f;
    for (int slot = sz; slot < nblk; slot += 16)
        acc += P[((size_t)(b * nblk + slot)) * 4224 + idx];
    P2[((size_t)(b * 16 + sz)) * 4224 + idx] = acc;
}

// K2b: final reduce -> R[b][4224]
__global__ __launch_bounds__(256) void reduce_p2(
    const float* __restrict__ P2, float* __restrict__ R)
{
    const int idx = blockIdx.x * 256 + threadIdx.x;
    if (idx >= 4224) return;
    const int b = blockIdx.y;
    float acc = 0.f;
#pragma unroll
    for (int s = 0; s < 16; ++s)
        acc += P2[((size_t)(b * 16 + s)) * 4224 + idx];
    R[b * 4224 + idx] = acc;
}

// K3: build Mt[c][o], parallelized over (o-slice=8, batch) = 16 blocks (R15).
__global__ __launch_bounds__(256) void build_M(
    const float* __restrict__ R, const float* __restrict__ Wout,
    const float* __restrict__ Wqkv, float* __restrict__ Mt)
{
    __shared__ float ctx[4096];          // [h][e][d] (transposed)
    __shared__ float Ash[8 * 128];       // A[oo][h*32+d]
    const int b = blockIdx.y;
    const int o0 = blockIdx.x * 8;
    const int tid = threadIdx.x;
    const float* Rb = R + b * 4224;
    for (int i = tid; i < 4096; i += 256) {
        const int hh = i >> 10, rr = i & 1023, e = rr >> 5, d = rr & 31;
        ctx[i] = Rb[hh * 1056 + d * 32 + e] / Rb[hh * 1056 + 1024 + d];
    }
    __syncthreads();
    for (int i = tid; i < 1024; i += 256) {
        const int oo = i >> 7, m = i & 127, hh = m >> 5, d = m & 31;
        float acc = 0.f;
#pragma unroll
        for (int e = 0; e < 32; ++e)
            acc += Wout[(o0 + oo) * 128 + hh * 32 + e] * ctx[hh * 1024 + e * 32 + d];
        Ash[i] = acc;
    }
    __syncthreads();
    const float scale = 0.17677669529663687f;
    for (int i = tid; i < 512; i += 256) {
        const int oo = i >> 6, c = i & 63;
        float acc = 0.f;
#pragma unroll
        for (int m = 0; m < 128; ++m)
            acc += Ash[oo * 128 + m] * Wqkv[m * 64 + c];
        Mt[b * 4096 + c * 64 + (o0 + oo)] = acc * scale;   // transposed store
    }
}

// K4: y[b,o,p] = sum_c Mt[c][o] x[b,c,p] + b_out[o]
__global__ __launch_bounds__(256, 4) void final_proj(
    const float* __restrict__ x, const float* __restrict__ Mt,
    const float* __restrict__ bout, float* __restrict__ y, int n)
{
    const int b = blockIdx.y;
    const int p = blockIdx.x * 256 + threadIdx.x;
    const float* xb = x + (size_t)b * CIN * n + p;
    const float* M = Mt + b * 4096;
    float acc[64];
#pragma unroll
    for (int o = 0; o < 64; ++o) acc[o] = bout[o];
    for (int c = 0; c < 64; ++c) {
        const float xv = xb[(size_t)c * n];
        const float* Mr = M + c * 64;
#pragma unroll
        for (int o = 0; o < 64; ++o) acc[o] += Mr[o] * xv;
    }
    float* yb = y + (size_t)b * CIN * n + p;
#pragma unroll
    for (int o = 0; o < 64; ++o) yb[(size_t)o * n] = acc[o];
}

extern "C" void kernel_launch(void* const* d_in, const int* in_sizes, int n_in,
                              void* d_out, int out_size, void* d_ws, size_t ws_size,
                              hipStream_t stream) {
    const float* x    = (const float*)d_in[0];
    const float* Wqkv = (const float*)d_in[1];
    const float* Wout = (const float*)d_in[2];
    const float* bout = (const float*)d_in[3];
    float* y = (float*)d_out;

    const int n = in_sizes[0] / 128;   // 110592
    const int nch = n / NP;            // 864

    // ws-adaptive partial-slot count
    int BLKX = 432;
    for (;;) {
        size_t need = 32768 + (size_t)2 * BLKX * 4224 * 4   // P
                    + (size_t)2 * 16 * 4224 * 4             // P2
                    + 2 * 4224 * 4 + 2 * 4096 * 4;          // R, Mt
        if (need <= ws_size || BLKX <= 64) break;
        BLKX = (BLKX == 432) ? 256 : (BLKX >> 1);
    }
    unsigned short* Wb = (unsigned short*)d_ws;                  // 32 KiB
    float* P  = (float*)((char*)d_ws + 32768);
    float* P2 = P + (size_t)2 * BLKX * 4224;
    float* R  = P2 + (size_t)2 * 16 * 4224;
    float* Mt = R + 2 * 4224;

    prep_w<<<8, 256, 0, stream>>>(Wqkv, Wb);
    lin_attn_ctx<<<dim3(2, 2, BLKX), 256, 0, stream>>>(x, Wb, P, n, nch);
    reduce_p1<<<dim3(17, 16, 2), 256, 0, stream>>>(P, P2, BLKX);
    reduce_p2<<<dim3(17, 2), 256, 0, stream>>>(P2, R);
    build_M<<<dim3(8, 2), 256, 0, stream>>>(R, Wout, Wqkv, Mt);
    final_proj<<<dim3(n / 256, 2), 256, 0, stream>>>(x, Mt, bout, y, n);
}

// Round 18
// 84.400 us; speedup vs baseline: 1.3384x; 1.0554x over previous
//
#include <hip/hip_runtime.h>
#include <math.h>

#define CIN 64
#define NP 128

typedef float f32x4 __attribute__((ext_vector_type(4)));
typedef short s16x8 __attribute__((ext_vector_type(8)));
typedef short s16x4 __attribute__((ext_vector_type(4)));

union FragU { s16x8 v; unsigned u[4]; };
union Frag4 { s16x4 v; unsigned u[2]; };

static __device__ __forceinline__ unsigned short f2b(float f) {
    unsigned u = __builtin_bit_cast(unsigned, f);
    unsigned r = (u + 0x7FFFu + ((u >> 16) & 1u)) >> 16;   // RNE (proven R1/R2/R5/R8)
    return (unsigned short)r;
}
// pack two f32 -> bf16x2 word, software RNE — NOT v_cvt_pk (R6: raw instr != RNE)
static __device__ __forceinline__ unsigned pack2(float lo, float hi) {
    return (unsigned)f2b(lo) | ((unsigned)f2b(hi) << 16);
}

// 16x16x16 bf16 MFMA (gfx950 instruction per ISA §10; carried-forward builtin)
static __device__ __forceinline__ f32x4 mfma16(s16x4 a, s16x4 b, f32x4 c) {
#if __has_builtin(__builtin_amdgcn_mfma_f32_16x16x16bf16_1k)
    return __builtin_amdgcn_mfma_f32_16x16x16bf16_1k(a, b, c, 0, 0, 0);
#else
    asm volatile("v_mfma_f32_16x16x16_bf16 %0, %1, %2, %0\n\ts_nop 7\n\ts_nop 7"
                 : "+v"(c) : "v"(a), "v"(b));
    return c;
#endif
}

// K0: pack W_k, W_v (rows 128..383 of Wqkv) into bf16 MFMA fragment tiles.
__global__ __launch_bounds__(256) void prep_w(const float* __restrict__ Wqkv,
                                              unsigned short* __restrict__ Wb) {
    int e0 = (blockIdx.x * 256 + threadIdx.x) * 8;   // < 16384
    int lane = (e0 >> 3) & 63;
    int kc = (e0 >> 9) & 1;
    int t = e0 >> 10;
    int row = 128 + t * 16 + (lane & 15);
    int c0 = kc * 32 + (lane >> 4) * 8;
    for (int j = 0; j < 8; ++j)
        Wb[e0 + j] = f2b(Wqkv[row * 64 + c0 + j]);
}

// K1: fused kv-projection + exp + context, all in registers; TWO heads/block
// (FETCH = 1x x, proven R17). R17 post-mortem: issue/latency-bound at ~152
// regs/wave -> 3 waves/SIMD. This round: REGISTER-PHASED inner loop — K-phase
// (only ak live) then V-phase (only av live), pinned by sched_barrier(0) —
// targets <=128 regs/wave -> 4 waves/SIMD. BLKX 432->216 amortizes the
// epilogue 2x (it was ~25% of block time at 2 chunks/block).
__global__ __launch_bounds__(256, 2) void lin_attn_ctx(
    const float* __restrict__ x, const unsigned short* __restrict__ Wb,
    float* __restrict__ P, int n, int nch)
{
    __shared__ float RED[4224];          // epilogue-only: 4x1024 ctx + 4x32 sums

    const int tid = threadIdx.x;
    const int l = tid & 63;
    const int w = tid >> 6;
    const int h0 = blockIdx.x * 2;       // head pair (fastest)
    const int b = blockIdx.y;            // batch
    const int slot = blockIdx.z;         // chunk slot
    const int nslot = gridDim.z;
    const int l15 = l & 15, lg = l >> 4;
    const uint4* Wb4 = (const uint4*)Wb;

    f32x4 zero4 = {0.f, 0.f, 0.f, 0.f};
    f32x4 ctx[2][2][2];                  // [hh][rt][vt]
    float sacc[2][2] = {{0.f, 0.f}, {0.f, 0.f}};
#pragma unroll
    for (int hh = 0; hh < 2; ++hh)
#pragma unroll
        for (int a = 0; a < 2; ++a)
#pragma unroll
            for (int c2 = 0; c2 < 2; ++c2) ctx[hh][a][c2] = zero4;

    const float* xw = x + (size_t)b * CIN * n;

    for (int ch = slot; ch < nch; ch += nslot) {
        // ---- direct global -> X-fragment loads, pack immediately (shared by both heads) ----
        const float* xp = xw + ch * NP + w * 32 + l15;
        s16x8 bx[2][2];
#pragma unroll
        for (int pt = 0; pt < 2; ++pt)
#pragma unroll
            for (int kc = 0; kc < 2; ++kc) {
                float xv[8];
#pragma unroll
                for (int j = 0; j < 8; ++j)
                    xv[j] = xp[(size_t)(kc * 32 + lg * 8 + j) * n + pt * 16];
                FragU fu;
#pragma unroll
                for (int i = 0; i < 4; ++i)
                    fu.u[i] = pack2(xv[2 * i], xv[2 * i + 1]);
                bx[pt][kc] = fu.v;
            }

#pragma unroll
        for (int hh = 0; hh < 2; ++hh) {
            const int h = h0 + hh;
            Frag4 ekf[2][2], vf[2][2];       // [pt][rt]
            // ---- K phase: only ak fragments live ----
            {
                s16x8 ak[2][2];
#pragma unroll
                for (int rt = 0; rt < 2; ++rt)
#pragma unroll
                    for (int kc = 0; kc < 2; ++kc)
                        ak[rt][kc] = *(const s16x8*)&Wb4[((2 * h + rt) * 2 + kc) * 64 + l];
#pragma unroll
                for (int pt = 0; pt < 2; ++pt)
#pragma unroll
                    for (int rt = 0; rt < 2; ++rt) {
                        f32x4 z = zero4;
                        z = __builtin_amdgcn_mfma_f32_16x16x32_bf16(bx[pt][0], ak[rt][0], z, 0, 0, 0);
                        z = __builtin_amdgcn_mfma_f32_16x16x32_bf16(bx[pt][1], ak[rt][1], z, 0, 0, 0);
                        float e0 = __expf(z[0]), e1 = __expf(z[1]);
                        float e2 = __expf(z[2]), e3 = __expf(z[3]);
                        sacc[hh][rt] += (e0 + e1) + (e2 + e3);
                        Frag4 fe; fe.u[0] = pack2(e0, e1); fe.u[1] = pack2(e2, e3);
                        ekf[pt][rt] = fe;
                    }
            }
            __builtin_amdgcn_sched_barrier(0);   // keep av loads out of K phase
            // ---- V phase: only av fragments live ----
            {
                s16x8 av[2][2];
#pragma unroll
                for (int rt = 0; rt < 2; ++rt)
#pragma unroll
                    for (int kc = 0; kc < 2; ++kc)
                        av[rt][kc] = *(const s16x8*)&Wb4[((8 + 2 * h + rt) * 2 + kc) * 64 + l];
#pragma unroll
                for (int pt = 0; pt < 2; ++pt)
#pragma unroll
                    for (int rt = 0; rt < 2; ++rt) {
                        f32x4 z2 = zero4;
                        z2 = __builtin_amdgcn_mfma_f32_16x16x32_bf16(bx[pt][0], av[rt][0], z2, 0, 0, 0);
                        z2 = __builtin_amdgcn_mfma_f32_16x16x32_bf16(bx[pt][1], av[rt][1], z2, 0, 0, 0);
                        Frag4 fv; fv.u[0] = pack2(z2[0], z2[1]); fv.u[1] = pack2(z2[2], z2[3]);
                        vf[pt][rt] = fv;
                    }
            }
            // ---- context: ctx[hh][rt][vt] += EK x V^T, K=pos ----
#pragma unroll
            for (int rt = 0; rt < 2; ++rt)
#pragma unroll
                for (int vt = 0; vt < 2; ++vt) {
                    ctx[hh][rt][vt] = mfma16(ekf[0][rt].v, vf[0][vt].v, ctx[hh][rt][vt]);
                    ctx[hh][rt][vt] = mfma16(ekf[1][rt].v, vf[1][vt].v, ctx[hh][rt][vt]);
                }
        }
    }

    // ---- cross-wave reduce, write both heads' partials ----
    float* Xf = RED;
    float* Sf = RED + 4096;
    float* Pb = P + (size_t)(b * nslot + slot) * 4224;
#pragma unroll
    for (int hh = 0; hh < 2; ++hh) {
        const int h = h0 + hh;
        __syncthreads();   // hh=0: trivial; hh=1: all waves done reading Xf
#pragma unroll
        for (int rt = 0; rt < 2; ++rt)
#pragma unroll
            for (int vt = 0; vt < 2; ++vt)
#pragma unroll
                for (int r = 0; r < 4; ++r) {
                    int d = rt * 16 + lg * 4 + r, e = vt * 16 + l15;
                    Xf[w * 1024 + d * 32 + e] = ctx[hh][rt][vt][r];
                }
#pragma unroll
        for (int rt = 0; rt < 2; ++rt) {
            float s = sacc[hh][rt];
            s += __shfl_xor(s, 16);
            s += __shfl_xor(s, 32);
            if (l < 16) Sf[w * 32 + rt * 16 + l15] = s;
        }
        __syncthreads();
        for (int i = tid; i < 1024; i += 256)
            Pb[h * 1056 + i] = Xf[i] + Xf[1024 + i] + Xf[2048 + i] + Xf[3072 + i];
        if (tid < 32)
            Pb[h * 1056 + 1024 + tid] = Sf[tid] + Sf[32 + tid] + Sf[64 + tid] + Sf[96 + tid];
    }
}

// K2a: slot-sliced partial reduce: P[b][slot][4224] -> P2[b][16][4224]
__global__ __launch_bounds__(256) void reduce_p1(
    const float* __restrict__ P, float* __restrict__ P2, int nblk)
{
    const int idx = blockIdx.x * 256 + threadIdx.x;
    if (idx >= 4224) return;
    const int b = blockIdx.z, sz = blockIdx.y;
    float acc = 0.f;
    for (int slot = sz; slot < nblk; slot += 16)
        acc += P[((size_t)(b * nblk + slot)) * 4224 + idx];
    P2[((size_t)(b * 16 + sz)) * 4224 + idx] = acc;
}

// K2b: final reduce -> R[b][4224]
__global__ __launch_bounds__(256) void reduce_p2(
    const float* __restrict__ P2, float* __restrict__ R)
{
    const int idx = blockIdx.x * 256 + threadIdx.x;
    if (idx >= 4224) return;
    const int b = blockIdx.y;
    float acc = 0.f;
#pragma unroll
    for (int s = 0; s < 16; ++s)
        acc += P2[((size_t)(b * 16 + s)) * 4224 + idx];
    R[b * 4224 + idx] = acc;
}

// K3: build Mt[c][o], parallelized over (o-slice=8, batch) = 16 blocks (R15).
__global__ __launch_bounds__(256) void build_M(
    const float* __restrict__ R, const float* __restrict__ Wout,
    const float* __restrict__ Wqkv, float* __restrict__ Mt)
{
    __shared__ float ctx[4096];          // [h][e][d] (transposed)
    __shared__ float Ash[8 * 128];       // A[oo][h*32+d]
    const int b = blockIdx.y;
    const int o0 = blockIdx.x * 8;
    const int tid = threadIdx.x;
    const float* Rb = R + b * 4224;
    for (int i = tid; i < 4096; i += 256) {
        const int hh = i >> 10, rr = i & 1023, e = rr >> 5, d = rr & 31;
        ctx[i] = Rb[hh * 1056 + d * 32 + e] / Rb[hh * 1056 + 1024 + d];
    }
    __syncthreads();
    for (int i = tid; i < 1024; i += 256) {
        const int oo = i >> 7, m = i & 127, hh = m >> 5, d = m & 31;
        float acc = 0.f;
#pragma unroll
        for (int e = 0; e < 32; ++e)
            acc += Wout[(o0 + oo) * 128 + hh * 32 + e] * ctx[hh * 1024 + e * 32 + d];
        Ash[i] = acc;
    }
    __syncthreads();
    const float scale = 0.17677669529663687f;
    for (int i = tid; i < 512; i += 256) {
        const int oo = i >> 6, c = i & 63;
        float acc = 0.f;
#pragma unroll
        for (int m = 0; m < 128; ++m)
            acc += Ash[oo * 128 + m] * Wqkv[m * 64 + c];
        Mt[b * 4096 + c * 64 + (o0 + oo)] = acc * scale;   // transposed store
    }
}

// K4: y[b,o,p] = sum_c Mt[c][o] x[b,c,p] + b_out[o]
__global__ __launch_bounds__(256, 4) void final_proj(
    const float* __restrict__ x, const float* __restrict__ Mt,
    const float* __restrict__ bout, float* __restrict__ y, int n)
{
    const int b = blockIdx.y;
    const int p = blockIdx.x * 256 + threadIdx.x;
    const float* xb = x + (size_t)b * CIN * n + p;
    const float* M = Mt + b * 4096;
    float acc[64];
#pragma unroll
    for (int o = 0; o < 64; ++o) acc[o] = bout[o];
    for (int c = 0; c < 64; ++c) {
        const float xv = xb[(size_t)c * n];
        const float* Mr = M + c * 64;
#pragma unroll
        for (int o = 0; o < 64; ++o) acc[o] += Mr[o] * xv;
    }
    float* yb = y + (size_t)b * CIN * n + p;
#pragma unroll
    for (int o = 0; o < 64; ++o) yb[(size_t)o * n] = acc[o];
}

extern "C" void kernel_launch(void* const* d_in, const int* in_sizes, int n_in,
                              void* d_out, int out_size, void* d_ws, size_t ws_size,
                              hipStream_t stream) {
    const float* x    = (const float*)d_in[0];
    const float* Wqkv = (const float*)d_in[1];
    const float* Wout = (const float*)d_in[2];
    const float* bout = (const float*)d_in[3];
    float* y = (float*)d_out;

    const int n = in_sizes[0] / 128;   // 110592
    const int nch = n / NP;            // 864

    // ws-adaptive partial-slot count (216 -> 4 chunks/block, epilogue amortized)
    int BLKX = 216;
    for (;;) {
        size_t need = 32768 + (size_t)2 * BLKX * 4224 * 4   // P
                    + (size_t)2 * 16 * 4224 * 4             // P2
                    + 2 * 4224 * 4 + 2 * 4096 * 4;          // R, Mt
        if (need <= ws_size || BLKX <= 64) break;
        BLKX >>= 1;
    }
    unsigned short* Wb = (unsigned short*)d_ws;                  // 32 KiB
    float* P  = (float*)((char*)d_ws + 32768);
    float* P2 = P + (size_t)2 * BLKX * 4224;
    float* R  = P2 + (size_t)2 * 16 * 4224;
    float* Mt = R + 2 * 4224;

    prep_w<<<8, 256, 0, stream>>>(Wqkv, Wb);
    lin_attn_ctx<<<dim3(2, 2, BLKX), 256, 0, stream>>>(x, Wb, P, n, nch);
    reduce_p1<<<dim3(17, 16, 2), 256, 0, stream>>>(P, P2, BLKX);
    reduce_p2<<<dim3(17, 2), 256, 0, stream>>>(P2, R);
    build_M<<<dim3(8, 2), 256, 0, stream>>>(R, Wout, Wqkv, Mt);
    final_proj<<<dim3(n / 256, 2), 256, 0, stream>>>(x, Mt, bout, y, n);
}

// Round 19
// 83.730 us; speedup vs baseline: 1.3491x; 1.0080x over previous
//
#include <hip/hip_runtime.h>
#include <math.h>

#define CIN 64
#define NP 128

typedef float f32x4 __attribute__((ext_vector_type(4)));
typedef short s16x8 __attribute__((ext_vector_type(8)));

union FragU { s16x8 v; unsigned u[4]; };

static __device__ __forceinline__ unsigned short f2b(float f) {
    unsigned u = __builtin_bit_cast(unsigned, f);
    unsigned r = (u + 0x7FFFu + ((u >> 16) & 1u)) >> 16;   // RNE (proven R1/R2/R5/R8)
    return (unsigned short)r;
}
// pack two f32 -> bf16x2 word, software RNE — NOT v_cvt_pk (R6: raw instr != RNE)
static __device__ __forceinline__ unsigned pack2(float lo, float hi) {
    return (unsigned)f2b(lo) | ((unsigned)f2b(hi) << 16);
}

// K0: pack W_k, W_v (rows 128..383 of Wqkv) into bf16 MFMA fragment tiles.
__global__ __launch_bounds__(256) void prep_w(const float* __restrict__ Wqkv,
                                              unsigned short* __restrict__ Wb) {
    int e0 = (blockIdx.x * 256 + threadIdx.x) * 8;   // < 16384
    int lane = (e0 >> 3) & 63;
    int kc = (e0 >> 9) & 1;
    int t = e0 >> 10;
    int row = 128 + t * 16 + (lane & 15);
    int c0 = kc * 32 + (lane >> 4) * 8;
    for (int j = 0; j < 8; ++j)
        Wb[e0 + j] = f2b(Wqkv[row * 64 + c0 + j]);
}

// K1: fused kv-projection + exp + context, all in registers; TWO heads/block.
// R19 change: chunk positions re-enumerated as pos = (i>>2)*8 + pt*4 + (i&3)
// so the two pt proj-tiles' packed outputs concatenate into the K=32 fragment
// layout (k = lg*8 + pt*4 + r) -> ctx uses ONE proven mfma_f32_16x16x32_bf16
// per (head,rt,vt) instead of two 16x16x16 helper calls (possible s_nop-laden
// asm fallback eliminated; 16->8 ctx MFMAs/chunk).
__global__ __launch_bounds__(256, 2) void lin_attn_ctx(
    const float* __restrict__ x, const unsigned short* __restrict__ Wb,
    float* __restrict__ P, int n, int nch)
{
    __shared__ float RED[4224];          // epilogue-only: 4x1024 ctx + 4x32 sums

    const int tid = threadIdx.x;
    const int l = tid & 63;
    const int w = tid >> 6;
    const int h0 = blockIdx.x * 2;       // head pair (fastest)
    const int b = blockIdx.y;            // batch
    const int slot = blockIdx.z;         // chunk slot
    const int nslot = gridDim.z;
    const int l15 = l & 15, lg = l >> 4;
    const uint4* Wb4 = (const uint4*)Wb;

    f32x4 zero4 = {0.f, 0.f, 0.f, 0.f};
    f32x4 ctx[2][2][2];                  // [hh][rt][vt]
    float sacc[2][2] = {{0.f, 0.f}, {0.f, 0.f}};
#pragma unroll
    for (int hh = 0; hh < 2; ++hh)
#pragma unroll
        for (int a = 0; a < 2; ++a)
#pragma unroll
            for (int c2 = 0; c2 < 2; ++c2) ctx[hh][a][c2] = zero4;

    const float* xw = x + (size_t)b * CIN * n;
    const int qbase = ((l15 >> 2) << 3) + (l15 & 3);   // remapped position (pt adds +4)

    for (int ch = slot; ch < nch; ch += nslot) {
        // ---- direct global -> X-fragment loads (remapped positions), pack ----
        const float* xp = xw + ch * NP + w * 32 + qbase;
        s16x8 bx[2][2];
#pragma unroll
        for (int pt = 0; pt < 2; ++pt)
#pragma unroll
            for (int kc = 0; kc < 2; ++kc) {
                float xv[8];
#pragma unroll
                for (int j = 0; j < 8; ++j)
                    xv[j] = xp[(size_t)(kc * 32 + lg * 8 + j) * n + pt * 4];
                FragU fu;
#pragma unroll
                for (int i = 0; i < 4; ++i)
                    fu.u[i] = pack2(xv[2 * i], xv[2 * i + 1]);
                bx[pt][kc] = fu.v;
            }

#pragma unroll
        for (int hh = 0; hh < 2; ++hh) {
            const int h = h0 + hh;
            FragU ea[2], va[2];          // [rt]: concat K=32 fragments (j = pt*4 + r)
            // ---- K phase: only ak fragments live ----
            {
                s16x8 ak[2][2];
#pragma unroll
                for (int rt = 0; rt < 2; ++rt)
#pragma unroll
                    for (int kc = 0; kc < 2; ++kc)
                        ak[rt][kc] = *(const s16x8*)&Wb4[((2 * h + rt) * 2 + kc) * 64 + l];
#pragma unroll
                for (int pt = 0; pt < 2; ++pt)
#pragma unroll
                    for (int rt = 0; rt < 2; ++rt) {
                        f32x4 z = zero4;
                        z = __builtin_amdgcn_mfma_f32_16x16x32_bf16(bx[pt][0], ak[rt][0], z, 0, 0, 0);
                        z = __builtin_amdgcn_mfma_f32_16x16x32_bf16(bx[pt][1], ak[rt][1], z, 0, 0, 0);
                        float e0 = __expf(z[0]), e1 = __expf(z[1]);
                        float e2 = __expf(z[2]), e3 = __expf(z[3]);
                        sacc[hh][rt] += (e0 + e1) + (e2 + e3);
                        ea[rt].u[pt * 2]     = pack2(e0, e1);
                        ea[rt].u[pt * 2 + 1] = pack2(e2, e3);
                    }
            }
            __builtin_amdgcn_sched_barrier(0);   // keep av loads out of K phase
            // ---- V phase: only av fragments live ----
            {
                s16x8 av[2][2];
#pragma unroll
                for (int rt = 0; rt < 2; ++rt)
#pragma unroll
                    for (int kc = 0; kc < 2; ++kc)
                        av[rt][kc] = *(const s16x8*)&Wb4[((8 + 2 * h + rt) * 2 + kc) * 64 + l];
#pragma unroll
                for (int pt = 0; pt < 2; ++pt)
#pragma unroll
                    for (int rt = 0; rt < 2; ++rt) {
                        f32x4 z2 = zero4;
                        z2 = __builtin_amdgcn_mfma_f32_16x16x32_bf16(bx[pt][0], av[rt][0], z2, 0, 0, 0);
                        z2 = __builtin_amdgcn_mfma_f32_16x16x32_bf16(bx[pt][1], av[rt][1], z2, 0, 0, 0);
                        va[rt].u[pt * 2]     = pack2(z2[0], z2[1]);
                        va[rt].u[pt * 2 + 1] = pack2(z2[2], z2[3]);
                    }
            }
            // ---- context: ONE K=32 MFMA per (rt,vt) ----
#pragma unroll
            for (int rt = 0; rt < 2; ++rt)
#pragma unroll
                for (int vt = 0; vt < 2; ++vt)
                    ctx[hh][rt][vt] = __builtin_amdgcn_mfma_f32_16x16x32_bf16(
                        ea[rt].v, va[vt].v, ctx[hh][rt][vt], 0, 0, 0);
        }
    }

    // ---- cross-wave reduce, write both heads' partials ----
    float* Xf = RED;
    float* Sf = RED + 4096;
    float* Pb = P + (size_t)(b * nslot + slot) * 4224;
#pragma unroll
    for (int hh = 0; hh < 2; ++hh) {
        const int h = h0 + hh;
        __syncthreads();   // hh=0: trivial; hh=1: all waves done reading Xf
#pragma unroll
        for (int rt = 0; rt < 2; ++rt)
#pragma unroll
            for (int vt = 0; vt < 2; ++vt)
#pragma unroll
                for (int r = 0; r < 4; ++r) {
                    int d = rt * 16 + lg * 4 + r, e = vt * 16 + l15;
                    Xf[w * 1024 + d * 32 + e] = ctx[hh][rt][vt][r];
                }
#pragma unroll
        for (int rt = 0; rt < 2; ++rt) {
            float s = sacc[hh][rt];
            s += __shfl_xor(s, 16);
            s += __shfl_xor(s, 32);
            if (l < 16) Sf[w * 32 + rt * 16 + l15] = s;
        }
        __syncthreads();
        for (int i = tid; i < 1024; i += 256)
            Pb[h * 1056 + i] = Xf[i] + Xf[1024 + i] + Xf[2048 + i] + Xf[3072 + i];
        if (tid < 32)
            Pb[h * 1056 + 1024 + tid] = Sf[tid] + Sf[32 + tid] + Sf[64 + tid] + Sf[96 + tid];
    }
}

// K2a: slot-sliced partial reduce: P[b][slot][4224] -> P2[b][16][4224]
__global__ __launch_bounds__(256) void reduce_p1(
    const float* __restrict__ P, float* __restrict__ P2, int nblk)
{
    const int idx = blockIdx.x * 256 + threadIdx.x;
    if (idx >= 4224) return;
    const int b = blockIdx.z, sz = blockIdx.y;
    float acc = 0.f;
    for (int slot = sz; slot < nblk; slot += 16)
        acc += P[((size_t)(b * nblk + slot)) * 4224 + idx];
    P2[((size_t)(b * 16 + sz)) * 4224 + idx] = acc;
}

// K2b: final reduce -> R[b][4224]
__global__ __launch_bounds__(256) void reduce_p2(
    const float* __restrict__ P2, float* __restrict__ R)
{
    const int idx = blockIdx.x * 256 + threadIdx.x;
    if (idx >= 4224) return;
    const int b = blockIdx.y;
    float acc = 0.f;
#pragma unroll
    for (int s = 0; s < 16; ++s)
        acc += P2[((size_t)(b * 16 + s)) * 4224 + idx];
    R[b * 4224 + idx] = acc;
}

// K3: build Mt[c][o], parallelized over (o-slice=8, batch) = 16 blocks (R15).
__global__ __launch_bounds__(256) void build_M(
    const float* __restrict__ R, const float* __restrict__ Wout,
    const float* __restrict__ Wqkv, float* __restrict__ Mt)
{
    __shared__ float ctx[4096];          // [h][e][d] (transposed)
    __shared__ float Ash[8 * 128];       // A[oo][h*32+d]
    const int b = blockIdx.y;
    const int o0 = blockIdx.x * 8;
    const int tid = threadIdx.x;
    const float* Rb = R + b * 4224;
    for (int i = tid; i < 4096; i += 256) {
        const int hh = i >> 10, rr = i & 1023, e = rr >> 5, d = rr & 31;
        ctx[i] = Rb[hh * 1056 + d * 32 + e] / Rb[hh * 1056 + 1024 + d];
    }
    __syncthreads();
    for (int i = tid; i < 1024; i += 256) {
        const int oo = i >> 7, m = i & 127, hh = m >> 5, d = m & 31;
        float acc = 0.f;
#pragma unroll
        for (int e = 0; e < 32; ++e)
            acc += Wout[(o0 + oo) * 128 + hh * 32 + e] * ctx[hh * 1024 + e * 32 + d];
        Ash[i] = acc;
    }
    __syncthreads();
    const float scale = 0.17677669529663687f;
    for (int i = tid; i < 512; i += 256) {
        const int oo = i >> 6, c = i & 63;
        float acc = 0.f;
#pragma unroll
        for (int m = 0; m < 128; ++m)
            acc += Ash[oo * 128 + m] * Wqkv[m * 64 + c];
        Mt[b * 4096 + c * 64 + (o0 + oo)] = acc * scale;   // transposed store
    }
}

// K4: y[b,o,p] = sum_c Mt[c][o] x[b,c,p] + b_out[o]
__global__ __launch_bounds__(256, 4) void final_proj(
    const float* __restrict__ x, const float* __restrict__ Mt,
    const float* __restrict__ bout, float* __restrict__ y, int n)
{
    const int b = blockIdx.y;
    const int p = blockIdx.x * 256 + threadIdx.x;
    const float* xb = x + (size_t)b * CIN * n + p;
    const float* M = Mt + b * 4096;
    float acc[64];
#pragma unroll
    for (int o = 0; o < 64; ++o) acc[o] = bout[o];
    for (int c = 0; c < 64; ++c) {
        const float xv = xb[(size_t)c * n];
        const float* Mr = M + c * 64;
#pragma unroll
        for (int o = 0; o < 64; ++o) acc[o] += Mr[o] * xv;
    }
    float* yb = y + (size_t)b * CIN * n + p;
#pragma unroll
    for (int o = 0; o < 64; ++o) yb[(size_t)o * n] = acc[o];
}

extern "C" void kernel_launch(void* const* d_in, const int* in_sizes, int n_in,
                              void* d_out, int out_size, void* d_ws, size_t ws_size,
                              hipStream_t stream) {
    const float* x    = (const float*)d_in[0];
    const float* Wqkv = (const float*)d_in[1];
    const float* Wout = (const float*)d_in[2];
    const float* bout = (const float*)d_in[3];
    float* y = (float*)d_out;

    const int n = in_sizes[0] / 128;   // 110592
    const int nch = n / NP;            // 864

    // ws-adaptive partial-slot count (216 -> 4 chunks/block)
    int BLKX = 216;
    for (;;) {
        size_t need = 32768 + (size_t)2 * BLKX * 4224 * 4   // P
                    + (size_t)2 * 16 * 4224 * 4             // P2
                    + 2 * 4224 * 4 + 2 * 4096 * 4;          // R, Mt
        if (need <= ws_size || BLKX <= 64) break;
        BLKX >>= 1;
    }
    unsigned short* Wb = (unsigned short*)d_ws;                  // 32 KiB
    float* P  = (float*)((char*)d_ws + 32768);
    float* P2 = P + (size_t)2 * BLKX * 4224;
    float* R  = P2 + (size_t)2 * 16 * 4224;
    float* Mt = R + 2 * 4224;

    prep_w<<<8, 256, 0, stream>>>(Wqkv, Wb);
    lin_attn_ctx<<<dim3(2, 2, BLKX), 256, 0, stream>>>(x, Wb, P, n, nch);
    reduce_p1<<<dim3(17, 16, 2), 256, 0, stream>>>(P, P2, BLKX);
    reduce_p2<<<dim3(17, 2), 256, 0, stream>>>(P2, R);
    build_M<<<dim3(8, 2), 256, 0, stream>>>(R, Wout, Wqkv, Mt);
    final_proj<<<dim3(n / 256, 2), 256, 0, stream>>>(x, Mt, bout, y, n);
}